// Round 1
// baseline (31473.581 us; speedup 1.0000x reference)
//
#include <hip/hip_runtime.h>
#include <stdint.h>
#include <math.h>

// ---------------------------------------------------------------------------
// SpikeICSPBLMMinimal: 128-step scan RNN. B=512, S=128, H=192, V=256, P=64, PH=16
// Kernel 1 (fold_k): algebraic folding + f16 k-pair packing of all weights
// Kernel 2 (rnn_k):  persistent per-batch-row scan; 128 blocks x 4 rows
// Kernel 3 (dec_k):  logits = hidden @ dec_W as parallel GEMM (deferred)
// ---------------------------------------------------------------------------

#define S_LEN 128
#define HD    192
#define VOC   256
#define PSL   64
#define PHD   16

// ws layout (in 4-byte elements)
#define OFF_SELTOK   0         // f32 [256][64]   tok@sel_W_tok + sel_b
#define OFF_BINDTOK  16384     // f32 [256][192]  tok@bind_W1_tok + bind_b1
#define OFF_SELWP    65536     // u32 [96][64]    sel_W prev-part, f16 k-pairs
#define OFF_PB       71680     // u32 [32][192]   PV@bind_W1_patch
#define OFF_BINDWP   77824     // u32 [96][192]   bind_W1 prev-part
#define OFF_BINDW2   96256     // u32 [96][192]
#define OFF_ROUTERW  114688    // u32 [192][16]   router_W (sec rows then prev rows)
#define OFF_PS       117760    // u32 [32][192]   PV@succ_W1_patch
#define OFF_PHS      123904    // u32 [8][192]    phase_embed@succ_W1_phs
#define OFF_SUCCWS   125440    // u32 [96][192]   succ_W1 sec-part
#define OFF_SUCCW2   143872    // u32 [96][192]
#define OFF_GATEW1   162304    // u32 [192][192]  gate_W1 (succ rows then prev rows)
#define OFF_DEC      199168    // u32 [96][256]   dec_W
#define WS_TOTAL     223744

typedef _Float16 h2 __attribute__((ext_vector_type(2)));

__device__ __forceinline__ float dot2f(unsigned w, unsigned x, float c) {
  h2 hw = __builtin_bit_cast(h2, w);
  h2 hx = __builtin_bit_cast(h2, x);
#if __has_builtin(__builtin_amdgcn_fdot2)
  return __builtin_amdgcn_fdot2(hw, hx, c, false);
#else
  return c + (float)hw.x * (float)hx.x + (float)hw.y * (float)hx.y;
#endif
}

__device__ __forceinline__ unsigned pk2(float a, float b) {
  _Float16 ha = (_Float16)a, hb = (_Float16)b;           // RTN converts
  unsigned short ua = __builtin_bit_cast(unsigned short, ha);
  unsigned short ub = __builtin_bit_cast(unsigned short, hb);
  return (unsigned)ua | ((unsigned)ub << 16);
}

__device__ __forceinline__ float geluf(float x) {
  return 0.5f * x * (1.0f + erff(x * 0.70710678118654752f));  // exact erf gelu
}

// ---------------------------------------------------------------------------
// fold kernel: region-dispatch by blockIdx.x (874 blocks x 256 threads)
// ---------------------------------------------------------------------------
__global__ __launch_bounds__(256) void fold_k(
    const float* __restrict__ emb,  const float* __restrict__ selW,
    const float* __restrict__ selb, const float* __restrict__ PV,
    const float* __restrict__ bW1,  const float* __restrict__ bb1,
    const float* __restrict__ bW2,  const float* __restrict__ phE,
    const float* __restrict__ rW,   const float* __restrict__ sW1,
    const float* __restrict__ sW2,  const float* __restrict__ gW1,
    const float* __restrict__ decW, float* __restrict__ ws)
{
  unsigned* wsu = (unsigned*)ws;
  int blk = blockIdx.x, tid = threadIdx.x;

  if (blk < 64) {                       // sel_tok [256][64] f32
    int o = blk * 256 + tid; int v = o >> 6, c = o & 63;
    float a = selb[c];
    const float* er = emb + v * HD;
    for (int h = 0; h < HD; ++h) a += er[h] * selW[h * PSL + c];
    ws[OFF_SELTOK + o] = a;
  } else if (blk < 256) {               // bind_tok [256][192] f32
    int o = (blk - 64) * 256 + tid; int v = o / HD, c = o % HD;
    float a = bb1[c];
    const float* er = emb + v * HD;
    for (int h = 0; h < HD; ++h) a += er[h] * bW1[h * HD + c];
    ws[OFF_BINDTOK + o] = a;
  } else if (blk < 280) {               // PB2: PV @ bind_W1[192:384]
    int o = (blk - 256) * 256 + tid; int k2 = o / HD, c = o % HD;
    float lo = 0.f, hi = 0.f;
    const float* p0 = PV + (2 * k2) * HD; const float* p1 = p0 + HD;
    for (int h = 0; h < HD; ++h) { float wv = bW1[(HD + h) * HD + c]; lo += p0[h] * wv; hi += p1[h] * wv; }
    wsu[OFF_PB + o] = pk2(lo, hi);
  } else if (blk < 304) {               // PS2: PV @ succ_W1[192:384]
    int o = (blk - 280) * 256 + tid; int k2 = o / HD, c = o % HD;
    float lo = 0.f, hi = 0.f;
    const float* p0 = PV + (2 * k2) * HD; const float* p1 = p0 + HD;
    for (int h = 0; h < HD; ++h) { float wv = sW1[(HD + h) * HD + c]; lo += p0[h] * wv; hi += p1[h] * wv; }
    wsu[OFF_PS + o] = pk2(lo, hi);
  } else if (blk < 310) {               // PhS2: phase_embed @ succ_W1[384:576]
    int o = (blk - 304) * 256 + tid; int k2 = o / HD, c = o % HD;
    float lo = 0.f, hi = 0.f;
    const float* p0 = phE + (2 * k2) * HD; const float* p1 = p0 + HD;
    for (int h = 0; h < HD; ++h) { float wv = sW1[(2 * HD + h) * HD + c]; lo += p0[h] * wv; hi += p1[h] * wv; }
    wsu[OFF_PHS + o] = pk2(lo, hi);
  } else if (blk < 334) {               // selWp2 [96][64] from sel_W rows 192..383
    int o = (blk - 310) * 256 + tid; int k2 = o >> 6, c = o & 63;
    wsu[OFF_SELWP + o] = pk2(selW[(HD + 2 * k2) * PSL + c], selW[(HD + 2 * k2 + 1) * PSL + c]);
  } else if (blk < 406) {               // bindWp2 [96][192] from bind_W1 rows 384..575
    int o = (blk - 334) * 256 + tid; int k2 = o / HD, c = o % HD;
    wsu[OFF_BINDWP + o] = pk2(bW1[(2 * HD + 2 * k2) * HD + c], bW1[(2 * HD + 2 * k2 + 1) * HD + c]);
  } else if (blk < 478) {               // bindW2p [96][192]
    int o = (blk - 406) * 256 + tid; int k2 = o / HD, c = o % HD;
    wsu[OFF_BINDW2 + o] = pk2(bW2[(2 * k2) * HD + c], bW2[(2 * k2 + 1) * HD + c]);
  } else if (blk < 490) {               // routerW2 [192][16] (rows 0..383 paired)
    int o = (blk - 478) * 256 + tid; int k2 = o >> 4, c = o & 15;
    wsu[OFF_ROUTERW + o] = pk2(rW[(2 * k2) * PHD + c], rW[(2 * k2 + 1) * PHD + c]);
  } else if (blk < 562) {               // succWs2 [96][192] from succ_W1 rows 0..191
    int o = (blk - 490) * 256 + tid; int k2 = o / HD, c = o % HD;
    wsu[OFF_SUCCWS + o] = pk2(sW1[(2 * k2) * HD + c], sW1[(2 * k2 + 1) * HD + c]);
  } else if (blk < 634) {               // succW2p [96][192]
    int o = (blk - 562) * 256 + tid; int k2 = o / HD, c = o % HD;
    wsu[OFF_SUCCW2 + o] = pk2(sW2[(2 * k2) * HD + c], sW2[(2 * k2 + 1) * HD + c]);
  } else if (blk < 778) {               // gateW12 [192][192] (rows 0..383 paired)
    int o = (blk - 634) * 256 + tid; int k2 = o / HD, c = o % HD;
    wsu[OFF_GATEW1 + o] = pk2(gW1[(2 * k2) * HD + c], gW1[(2 * k2 + 1) * HD + c]);
  } else {                              // dec2 [96][256]
    int o = (blk - 778) * 256 + tid; int k2 = o >> 8, c = o & 255;
    wsu[OFF_DEC + o] = pk2(decW[(2 * k2) * VOC + c], decW[(2 * k2 + 1) * VOC + c]);
  }
}

// ---------------------------------------------------------------------------
// mm4: 4-row dot2 accumulation. wp pre-offset by column; x is LDS f16-pair
// buffer (row stride xs u32). nk4 chunks of 4 k-pairs.
// ---------------------------------------------------------------------------
__device__ __forceinline__ void mm4(const unsigned* __restrict__ wp, int ldw, int nk4,
                                    const unsigned* __restrict__ x, int xs, float acc[4])
{
  for (int kk = 0; kk < nk4; ++kk) {
    unsigned w0 = wp[0], w1 = wp[ldw], w2 = wp[2 * ldw], w3 = wp[3 * ldw];
    wp += 4 * ldw;
    const unsigned* xp = x + kk * 4;
#pragma unroll
    for (int r = 0; r < 4; ++r) {
      uint4 xv = *reinterpret_cast<const uint4*>(xp + r * xs);
      acc[r] = dot2f(w0, xv.x, acc[r]);
      acc[r] = dot2f(w1, xv.y, acc[r]);
      acc[r] = dot2f(w2, xv.z, acc[r]);
      acc[r] = dot2f(w3, xv.w, acc[r]);
    }
  }
}

// ---------------------------------------------------------------------------
// rnn kernel: 128 blocks x 256 threads, 4 batch rows per block, 128 steps
// ---------------------------------------------------------------------------
__global__ __launch_bounds__(256) void rnn_k(
    const int* __restrict__ ids, const float* __restrict__ ws,
    const float* __restrict__ bind_b2, const float* __restrict__ router_b,
    const float* __restrict__ succ_b1, const float* __restrict__ succ_b2,
    const float* __restrict__ gate_b1, const float* __restrict__ gate_W2,
    const float* __restrict__ gate_b2, const float* __restrict__ ln_g,
    const float* __restrict__ ln_b,
    float* __restrict__ out_hidden, float* __restrict__ out_pw,
    float* __restrict__ out_phw, float* __restrict__ out_gate)
{
  const unsigned* wsu = (const unsigned*)ws;
  const float* sel_tok  = ws + OFF_SELTOK;
  const float* bind_tok = ws + OFF_BINDTOK;
  const unsigned* selWp   = wsu + OFF_SELWP;
  const unsigned* PB      = wsu + OFF_PB;
  const unsigned* bindWp  = wsu + OFF_BINDWP;
  const unsigned* bindW2  = wsu + OFF_BINDW2;
  const unsigned* routerW = wsu + OFF_ROUTERW;
  const unsigned* PS      = wsu + OFF_PS;
  const unsigned* PhS     = wsu + OFF_PHS;
  const unsigned* succWs  = wsu + OFF_SUCCWS;
  const unsigned* succW2  = wsu + OFF_SUCCW2;
  const unsigned* gateW1  = wsu + OFF_GATEW1;

  __shared__ __align__(16) float    s_prev[4][HD];
  __shared__ __align__(16) unsigned s_prevh[4][96];
  __shared__ __align__(16) unsigned s_sech[4][96];
  __shared__ __align__(16) unsigned s_xh[4][96];
  __shared__ __align__(16) float    s_succ[4][HD];
  __shared__ __align__(16) unsigned s_succh[4][96];
  __shared__ __align__(16) unsigned s_pwh[4][32];
  __shared__ __align__(16) unsigned s_phwh[4][8];
  __shared__ __align__(16) float    s_part[1024];
  __shared__ __align__(16) float    s_gpart[HD * 4];
  __shared__ int s_tok[4];

  const int tid = threadIdx.x;
  const int b0  = blockIdx.x * 4;
  const int w   = tid >> 6, lane = tid & 63;

  for (int i = tid; i < 4 * HD; i += 256) s_prev[i / HD][i % HD] = 0.f;
  for (int i = tid; i < 4 * 96; i += 256) s_prevh[i / 96][i % 96] = 0u;
  __syncthreads();

  for (int t = 0; t < S_LEN; ++t) {
    if (tid < 4) s_tok[tid] = ids[(b0 + tid) * S_LEN + t];
    __syncthreads();

    // ---- P1: sel pre-activation (prev part), 4 k-slices x 64 cols ----
    {
      int c = tid & 63, sl = tid >> 6;
      float acc[4] = {0.f, 0.f, 0.f, 0.f};
      mm4(selWp + (sl * 24) * PSL + c, PSL, 6, &s_prevh[0][sl * 24], 96, acc);
#pragma unroll
      for (int r = 0; r < 4; ++r) s_part[(((sl << 6) | c) << 2) + r] = acc[r];
    }
    __syncthreads();

    // ---- P2: sel softmax (wave w = row w, 64 lanes = 64 patch slots) ----
    {
      int c = lane;
      float a = sel_tok[s_tok[w] * PSL + c];
#pragma unroll
      for (int s = 0; s < 4; ++s) a += s_part[(((s << 6) | c) << 2) + w];
      float mx = a;
#pragma unroll
      for (int m = 32; m; m >>= 1) mx = fmaxf(mx, __shfl_xor(mx, m));
      float e = expf(a - mx);
      float sm = e;
#pragma unroll
      for (int m = 32; m; m >>= 1) sm += __shfl_xor(sm, m);
      float pv = e / sm;
      out_pw[(size_t)((b0 + w) * S_LEN + t) * PSL + c] = pv;
      float ov = __shfl_xor(pv, 1);
      if (!(c & 1)) s_pwh[w][c >> 1] = pk2(pv, ov);
    }
    __syncthreads();

    // ---- P3: bind1 = tok_table + pw@PB + prev@bindWp; gelu ----
    if (tid < HD) {
      int c = tid;
      float acc[4];
#pragma unroll
      for (int r = 0; r < 4; ++r) acc[r] = bind_tok[s_tok[r] * HD + c];
      mm4(PB + c, HD, 8, &s_pwh[0][0], 32, acc);
      mm4(bindWp + c, HD, 24, &s_prevh[0][0], 96, acc);
#pragma unroll
      for (int r = 0; r < 4; ++r) {
        float g = geluf(acc[r]);
        float o = __shfl_xor(g, 1);
        if (!(c & 1)) s_xh[r][c >> 1] = pk2(g, o);
      }
    }
    __syncthreads();

    // ---- P4: bind2 + tanh -> sec ----
    if (tid < HD) {
      int c = tid;
      float acc[4];
#pragma unroll
      for (int r = 0; r < 4; ++r) acc[r] = bind_b2[c];
      mm4(bindW2 + c, HD, 24, &s_xh[0][0], 96, acc);
#pragma unroll
      for (int r = 0; r < 4; ++r) {
        float sv = tanhf(acc[r]);
        float o = __shfl_xor(sv, 1);
        if (!(c & 1)) s_sech[r][c >> 1] = pk2(sv, o);
      }
    }
    __syncthreads();

    // ---- P5: router pre-activation, 16 k-slices x 16 cols ----
    {
      int c = tid & 15, sl = tid >> 4;
      float acc[4] = {0.f, 0.f, 0.f, 0.f};
      const unsigned* xb = (sl < 8) ? &s_sech[0][sl * 12] : &s_prevh[0][(sl - 8) * 12];
      mm4(routerW + (sl * 12) * PHD + c, PHD, 3, xb, 96, acc);
#pragma unroll
      for (int r = 0; r < 4; ++r) s_part[(((sl << 4) | c) << 2) + r] = acc[r];
    }
    __syncthreads();

    // ---- P6: router softmax (wave w = row w, lanes 0..15) ----
    if (lane < PHD) {
      int c = lane;
      float a = router_b[c];
#pragma unroll
      for (int s = 0; s < 16; ++s) a += s_part[(((s << 4) | c) << 2) + w];
      float mx = a;
#pragma unroll
      for (int m = 8; m; m >>= 1) mx = fmaxf(mx, __shfl_xor(mx, m));
      float e = expf(a - mx);
      float sm = e;
#pragma unroll
      for (int m = 8; m; m >>= 1) sm += __shfl_xor(sm, m);
      float ph = e / sm;
      out_phw[(size_t)((b0 + w) * S_LEN + t) * PHD + c] = ph;
      float ov = __shfl_xor(ph, 1);
      if (!(c & 1)) s_phwh[w][c >> 1] = pk2(ph, ov);
    }
    __syncthreads();

    // ---- P7: succ1 = sec@succWs + pw@PS + phw@PhS + b; gelu ----
    if (tid < HD) {
      int c = tid;
      float acc[4];
#pragma unroll
      for (int r = 0; r < 4; ++r) acc[r] = succ_b1[c];
      mm4(succWs + c, HD, 24, &s_sech[0][0], 96, acc);
      mm4(PS + c, HD, 8, &s_pwh[0][0], 32, acc);
      mm4(PhS + c, HD, 2, &s_phwh[0][0], 8, acc);
#pragma unroll
      for (int r = 0; r < 4; ++r) {
        float g = geluf(acc[r]);
        float o = __shfl_xor(g, 1);
        if (!(c & 1)) s_xh[r][c >> 1] = pk2(g, o);
      }
    }
    __syncthreads();

    // ---- P8: succ2 + tanh -> succ (f32 + f16) ----
    if (tid < HD) {
      int c = tid;
      float acc[4];
#pragma unroll
      for (int r = 0; r < 4; ++r) acc[r] = succ_b2[c];
      mm4(succW2 + c, HD, 24, &s_xh[0][0], 96, acc);
#pragma unroll
      for (int r = 0; r < 4; ++r) {
        float sv = tanhf(acc[r]);
        s_succ[r][c] = sv;
        float o = __shfl_xor(sv, 1);
        if (!(c & 1)) s_succh[r][c >> 1] = pk2(sv, o);
      }
    }
    __syncthreads();

    // ---- P9: gate1 = [succ,prev]@gate_W1 + b; gelu; * gate_W2[c] ----
    if (tid < HD) {
      int c = tid;
      float acc[4];
#pragma unroll
      for (int r = 0; r < 4; ++r) acc[r] = gate_b1[c];
      mm4(gateW1 + c, HD, 24, &s_succh[0][0], 96, acc);
      mm4(gateW1 + 96 * HD + c, HD, 24, &s_prevh[0][0], 96, acc);
      float w2c = gate_W2[c];
#pragma unroll
      for (int r = 0; r < 4; ++r) s_gpart[(c << 2) + r] = geluf(acc[r]) * w2c;
    }
    __syncthreads();

    // ---- P10+P11: gate reduce, blend, LayerNorm (wave w = row w) ----
    {
      float gp = s_gpart[(lane << 2) + w] + s_gpart[((lane + 64) << 2) + w]
               + s_gpart[((lane + 128) << 2) + w];
#pragma unroll
      for (int m = 32; m; m >>= 1) gp += __shfl_xor(gp, m);
      float gv = 1.f / (1.f + expf(-(gp + gate_b2[0])));
      if (lane == 0) out_gate[(size_t)(b0 + w) * S_LEN + t] = gv;

      int c0 = lane, c1 = lane + 64, c2 = lane + 128;
      float h0 = gv * s_succ[w][c0] + (1.f - gv) * s_prev[w][c0];
      float h1 = gv * s_succ[w][c1] + (1.f - gv) * s_prev[w][c1];
      float h2v = gv * s_succ[w][c2] + (1.f - gv) * s_prev[w][c2];
      float sum = h0 + h1 + h2v;
#pragma unroll
      for (int m = 32; m; m >>= 1) sum += __shfl_xor(sum, m);
      float mean = sum * (1.f / 192.f);
      float d0 = h0 - mean, d1 = h1 - mean, d2 = h2v - mean;
      float vs = d0 * d0 + d1 * d1 + d2 * d2;
#pragma unroll
      for (int m = 32; m; m >>= 1) vs += __shfl_xor(vs, m);
      float rstd = rsqrtf(vs * (1.f / 192.f) + 1e-5f);
      float y0 = d0 * rstd * ln_g[c0] + ln_b[c0];
      float y1 = d1 * rstd * ln_g[c1] + ln_b[c1];
      float y2 = d2 * rstd * ln_g[c2] + ln_b[c2];
      size_t ho = (size_t)((b0 + w) * S_LEN + t) * HD;
      out_hidden[ho + c0] = y0;
      out_hidden[ho + c1] = y1;
      out_hidden[ho + c2] = y2;
      s_prev[w][c0] = y0; s_prev[w][c1] = y1; s_prev[w][c2] = y2;
      float o0 = __shfl_xor(y0, 1), o1 = __shfl_xor(y1, 1), o2 = __shfl_xor(y2, 1);
      if (!(lane & 1)) {
        s_prevh[w][c0 >> 1] = pk2(y0, o0);
        s_prevh[w][c1 >> 1] = pk2(y1, o1);
        s_prevh[w][c2 >> 1] = pk2(y2, o2);
      }
    }
    __syncthreads();
  }
}

// ---------------------------------------------------------------------------
// dec kernel: logits[65536,256] = hidden[65536,192] @ dec_W[192,256]
// 1024 blocks x 256 threads; 64 rows per block; dec_W column in registers
// ---------------------------------------------------------------------------
__global__ __launch_bounds__(256) void dec_k(
    const float* __restrict__ hid, const unsigned* __restrict__ dec2,
    float* __restrict__ logits)
{
  __shared__ __align__(16) unsigned sA[64][96];
  int tid = threadIdx.x;
  size_t r0 = (size_t)blockIdx.x * 64;

#pragma unroll
  for (int i = 0; i < 24; ++i) {
    int idx = i * 256 + tid;
    int rr = idx / 96, kk = idx % 96;
    const float2* hp = (const float2*)(hid + (r0 + rr) * HD);
    float2 v = hp[kk];
    sA[rr][kk] = pk2(v.x, v.y);
  }
  __syncthreads();

  int c = tid;
  unsigned wr[96];
#pragma unroll
  for (int k = 0; k < 96; ++k) wr[k] = dec2[k * VOC + c];

  for (int rr = 0; rr < 64; ++rr) {
    float acc = 0.f;
#pragma unroll
    for (int k4 = 0; k4 < 24; ++k4) {
      uint4 xv = *reinterpret_cast<const uint4*>(&sA[rr][k4 * 4]);
      acc = dot2f(wr[4 * k4 + 0], xv.x, acc);
      acc = dot2f(wr[4 * k4 + 1], xv.y, acc);
      acc = dot2f(wr[4 * k4 + 2], xv.z, acc);
      acc = dot2f(wr[4 * k4 + 3], xv.w, acc);
    }
    logits[(r0 + rr) * VOC + c] = acc;
  }
}

// ---------------------------------------------------------------------------
extern "C" void kernel_launch(void* const* d_in, const int* in_sizes, int n_in,
                              void* d_out, int out_size, void* d_ws, size_t ws_size,
                              hipStream_t stream)
{
  const int*   ids  = (const int*)d_in[0];
  const float* emb  = (const float*)d_in[1];
  const float* selW = (const float*)d_in[2];
  const float* selb = (const float*)d_in[3];
  const float* PV   = (const float*)d_in[4];
  const float* bW1  = (const float*)d_in[5];
  const float* bb1  = (const float*)d_in[6];
  const float* bW2  = (const float*)d_in[7];
  const float* bb2  = (const float*)d_in[8];
  const float* phE  = (const float*)d_in[9];
  const float* rW   = (const float*)d_in[10];
  const float* rb   = (const float*)d_in[11];
  const float* sW1  = (const float*)d_in[12];
  const float* sb1  = (const float*)d_in[13];
  const float* sW2  = (const float*)d_in[14];
  const float* sb2  = (const float*)d_in[15];
  const float* gW1  = (const float*)d_in[16];
  const float* gb1  = (const float*)d_in[17];
  const float* gW2  = (const float*)d_in[18];
  const float* gb2  = (const float*)d_in[19];
  const float* lng  = (const float*)d_in[20];
  const float* lnb  = (const float*)d_in[21];
  const float* decW = (const float*)d_in[22];

  float* out = (float*)d_out;
  float* o_logits = out;                         // [512][128][256]
  float* o_hidden = out + 16777216;              // [512][128][192]
  float* o_pw     = out + 29360128;              // [512][128][64]
  float* o_phw    = out + 33554432;              // [512][128][16]
  float* o_gate   = out + 34603008;              // [512][128][1]

  float* ws = (float*)d_ws;

  hipLaunchKernelGGL(fold_k, dim3(874), dim3(256), 0, stream,
                     emb, selW, selb, PV, bW1, bb1, bW2, phE, rW, sW1, sW2, gW1, decW, ws);
  hipLaunchKernelGGL(rnn_k, dim3(128), dim3(256), 0, stream,
                     ids, ws, bb2, rb, sb1, sb2, gb1, gW2, gb2, lng, lnb,
                     o_hidden, o_pw, o_phw, o_gate);
  hipLaunchKernelGGL(dec_k, dim3(1024), dim3(256), 0, stream,
                     o_hidden, ((const unsigned*)d_ws) + OFF_DEC, o_logits);
}

// Round 2
// 4125.897 us; speedup vs baseline: 7.6283x; 7.6283x over previous
//
#include <hip/hip_runtime.h>
#include <stdint.h>
#include <math.h>

// ---------------------------------------------------------------------------
// SpikeICSPBLMMinimal: 128-step scan RNN. B=512, S=128, H=192, V=256, P=64, PH=16
// Kernel 1 (fold_k): algebraic folding + f16 k-pair packing of all weights
// Kernel 2 (rnn_k):  persistent per-batch-row scan; 128 blocks x 4 rows
// Kernel 3 (dec_k):  logits = hidden @ dec_W as parallel GEMM (deferred)
//
// R1 changes: (a) #pragma unroll 2 on mm4 k-loop — full unroll was spilling
// ~250 dwords/thread/step (WRITE_SIZE 4.24GB of scratch), and the per-XCD
// 4MB scratch working set thrashed L2 so weights missed every step.
// (b) s_part/s_gpart layout -> [row][slice*C+col] (lane-consecutive, no
// stride-16B 8-way LDS write conflicts).
// ---------------------------------------------------------------------------

#define S_LEN 128
#define HD    192
#define VOC   256
#define PSL   64
#define PHD   16

// ws layout (in 4-byte elements)
#define OFF_SELTOK   0         // f32 [256][64]   tok@sel_W_tok + sel_b
#define OFF_BINDTOK  16384     // f32 [256][192]  tok@bind_W1_tok + bind_b1
#define OFF_SELWP    65536     // u32 [96][64]    sel_W prev-part, f16 k-pairs
#define OFF_PB       71680     // u32 [32][192]   PV@bind_W1_patch
#define OFF_BINDWP   77824     // u32 [96][192]   bind_W1 prev-part
#define OFF_BINDW2   96256     // u32 [96][192]
#define OFF_ROUTERW  114688    // u32 [192][16]   router_W (sec rows then prev rows)
#define OFF_PS       117760    // u32 [32][192]   PV@succ_W1_patch
#define OFF_PHS      123904    // u32 [8][192]    phase_embed@succ_W1_phs
#define OFF_SUCCWS   125440    // u32 [96][192]   succ_W1 sec-part
#define OFF_SUCCW2   143872    // u32 [96][192]
#define OFF_GATEW1   162304    // u32 [192][192]  gate_W1 (succ rows then prev rows)
#define OFF_DEC      199168    // u32 [96][256]   dec_W
#define WS_TOTAL     223744

typedef _Float16 h2 __attribute__((ext_vector_type(2)));

__device__ __forceinline__ float dot2f(unsigned w, unsigned x, float c) {
  h2 hw = __builtin_bit_cast(h2, w);
  h2 hx = __builtin_bit_cast(h2, x);
#if __has_builtin(__builtin_amdgcn_fdot2)
  return __builtin_amdgcn_fdot2(hw, hx, c, false);
#else
  return c + (float)hw.x * (float)hx.x + (float)hw.y * (float)hx.y;
#endif
}

__device__ __forceinline__ unsigned pk2(float a, float b) {
  _Float16 ha = (_Float16)a, hb = (_Float16)b;           // RTN converts
  unsigned short ua = __builtin_bit_cast(unsigned short, ha);
  unsigned short ub = __builtin_bit_cast(unsigned short, hb);
  return (unsigned)ua | ((unsigned)ub << 16);
}

__device__ __forceinline__ float geluf(float x) {
  return 0.5f * x * (1.0f + erff(x * 0.70710678118654752f));  // exact erf gelu
}

// ---------------------------------------------------------------------------
// fold kernel: region-dispatch by blockIdx.x (874 blocks x 256 threads)
// ---------------------------------------------------------------------------
__global__ __launch_bounds__(256) void fold_k(
    const float* __restrict__ emb,  const float* __restrict__ selW,
    const float* __restrict__ selb, const float* __restrict__ PV,
    const float* __restrict__ bW1,  const float* __restrict__ bb1,
    const float* __restrict__ bW2,  const float* __restrict__ phE,
    const float* __restrict__ rW,   const float* __restrict__ sW1,
    const float* __restrict__ sW2,  const float* __restrict__ gW1,
    const float* __restrict__ decW, float* __restrict__ ws)
{
  unsigned* wsu = (unsigned*)ws;
  int blk = blockIdx.x, tid = threadIdx.x;

  if (blk < 64) {                       // sel_tok [256][64] f32
    int o = blk * 256 + tid; int v = o >> 6, c = o & 63;
    float a = selb[c];
    const float* er = emb + v * HD;
    for (int h = 0; h < HD; ++h) a += er[h] * selW[h * PSL + c];
    ws[OFF_SELTOK + o] = a;
  } else if (blk < 256) {               // bind_tok [256][192] f32
    int o = (blk - 64) * 256 + tid; int v = o / HD, c = o % HD;
    float a = bb1[c];
    const float* er = emb + v * HD;
    for (int h = 0; h < HD; ++h) a += er[h] * bW1[h * HD + c];
    ws[OFF_BINDTOK + o] = a;
  } else if (blk < 280) {               // PB2: PV @ bind_W1[192:384]
    int o = (blk - 256) * 256 + tid; int k2 = o / HD, c = o % HD;
    float lo = 0.f, hi = 0.f;
    const float* p0 = PV + (2 * k2) * HD; const float* p1 = p0 + HD;
    for (int h = 0; h < HD; ++h) { float wv = bW1[(HD + h) * HD + c]; lo += p0[h] * wv; hi += p1[h] * wv; }
    wsu[OFF_PB + o] = pk2(lo, hi);
  } else if (blk < 304) {               // PS2: PV @ succ_W1[192:384]
    int o = (blk - 280) * 256 + tid; int k2 = o / HD, c = o % HD;
    float lo = 0.f, hi = 0.f;
    const float* p0 = PV + (2 * k2) * HD; const float* p1 = p0 + HD;
    for (int h = 0; h < HD; ++h) { float wv = sW1[(HD + h) * HD + c]; lo += p0[h] * wv; hi += p1[h] * wv; }
    wsu[OFF_PS + o] = pk2(lo, hi);
  } else if (blk < 310) {               // PhS2: phase_embed @ succ_W1[384:576]
    int o = (blk - 304) * 256 + tid; int k2 = o / HD, c = o % HD;
    float lo = 0.f, hi = 0.f;
    const float* p0 = phE + (2 * k2) * HD; const float* p1 = p0 + HD;
    for (int h = 0; h < HD; ++h) { float wv = sW1[(2 * HD + h) * HD + c]; lo += p0[h] * wv; hi += p1[h] * wv; }
    wsu[OFF_PHS + o] = pk2(lo, hi);
  } else if (blk < 334) {               // selWp2 [96][64] from sel_W rows 192..383
    int o = (blk - 310) * 256 + tid; int k2 = o >> 6, c = o & 63;
    wsu[OFF_SELWP + o] = pk2(selW[(HD + 2 * k2) * PSL + c], selW[(HD + 2 * k2 + 1) * PSL + c]);
  } else if (blk < 406) {               // bindWp2 [96][192] from bind_W1 rows 384..575
    int o = (blk - 334) * 256 + tid; int k2 = o / HD, c = o % HD;
    wsu[OFF_BINDWP + o] = pk2(bW1[(2 * HD + 2 * k2) * HD + c], bW1[(2 * HD + 2 * k2 + 1) * HD + c]);
  } else if (blk < 478) {               // bindW2p [96][192]
    int o = (blk - 406) * 256 + tid; int k2 = o / HD, c = o % HD;
    wsu[OFF_BINDW2 + o] = pk2(bW2[(2 * k2) * HD + c], bW2[(2 * k2 + 1) * HD + c]);
  } else if (blk < 490) {               // routerW2 [192][16] (rows 0..383 paired)
    int o = (blk - 478) * 256 + tid; int k2 = o >> 4, c = o & 15;
    wsu[OFF_ROUTERW + o] = pk2(rW[(2 * k2) * PHD + c], rW[(2 * k2 + 1) * PHD + c]);
  } else if (blk < 562) {               // succWs2 [96][192] from succ_W1 rows 0..191
    int o = (blk - 490) * 256 + tid; int k2 = o / HD, c = o % HD;
    wsu[OFF_SUCCWS + o] = pk2(sW1[(2 * k2) * HD + c], sW1[(2 * k2 + 1) * HD + c]);
  } else if (blk < 634) {               // succW2p [96][192]
    int o = (blk - 562) * 256 + tid; int k2 = o / HD, c = o % HD;
    wsu[OFF_SUCCW2 + o] = pk2(sW2[(2 * k2) * HD + c], sW2[(2 * k2 + 1) * HD + c]);
  } else if (blk < 778) {               // gateW12 [192][192] (rows 0..383 paired)
    int o = (blk - 634) * 256 + tid; int k2 = o / HD, c = o % HD;
    wsu[OFF_GATEW1 + o] = pk2(gW1[(2 * k2) * HD + c], gW1[(2 * k2 + 1) * HD + c]);
  } else {                              // dec2 [96][256]
    int o = (blk - 778) * 256 + tid; int k2 = o >> 8, c = o & 255;
    wsu[OFF_DEC + o] = pk2(decW[(2 * k2) * VOC + c], decW[(2 * k2 + 1) * VOC + c]);
  }
}

// ---------------------------------------------------------------------------
// mm4: 4-row dot2 accumulation. wp pre-offset by column; x is LDS f16-pair
// buffer (row stride xs u32). nk4 chunks of 4 k-pairs.
// unroll 2: full unroll (trip counts are compile-time) spilled ~250 dw/thread
// ---------------------------------------------------------------------------
__device__ __forceinline__ void mm4(const unsigned* __restrict__ wp, int ldw, int nk4,
                                    const unsigned* __restrict__ x, int xs, float acc[4])
{
#pragma unroll 2
  for (int kk = 0; kk < nk4; ++kk) {
    unsigned w0 = wp[0], w1 = wp[ldw], w2 = wp[2 * ldw], w3 = wp[3 * ldw];
    wp += 4 * ldw;
    const unsigned* xp = x + kk * 4;
#pragma unroll
    for (int r = 0; r < 4; ++r) {
      uint4 xv = *reinterpret_cast<const uint4*>(xp + r * xs);
      acc[r] = dot2f(w0, xv.x, acc[r]);
      acc[r] = dot2f(w1, xv.y, acc[r]);
      acc[r] = dot2f(w2, xv.z, acc[r]);
      acc[r] = dot2f(w3, xv.w, acc[r]);
    }
  }
}

// ---------------------------------------------------------------------------
// rnn kernel: 128 blocks x 256 threads, 4 batch rows per block, 128 steps
// ---------------------------------------------------------------------------
__global__ __launch_bounds__(256) void rnn_k(
    const int* __restrict__ ids, const float* __restrict__ ws,
    const float* __restrict__ bind_b2, const float* __restrict__ router_b,
    const float* __restrict__ succ_b1, const float* __restrict__ succ_b2,
    const float* __restrict__ gate_b1, const float* __restrict__ gate_W2,
    const float* __restrict__ gate_b2, const float* __restrict__ ln_g,
    const float* __restrict__ ln_b,
    float* __restrict__ out_hidden, float* __restrict__ out_pw,
    float* __restrict__ out_phw, float* __restrict__ out_gate)
{
  const unsigned* wsu = (const unsigned*)ws;
  const float* sel_tok  = ws + OFF_SELTOK;
  const float* bind_tok = ws + OFF_BINDTOK;
  const unsigned* selWp   = wsu + OFF_SELWP;
  const unsigned* PB      = wsu + OFF_PB;
  const unsigned* bindWp  = wsu + OFF_BINDWP;
  const unsigned* bindW2  = wsu + OFF_BINDW2;
  const unsigned* routerW = wsu + OFF_ROUTERW;
  const unsigned* PS      = wsu + OFF_PS;
  const unsigned* PhS     = wsu + OFF_PHS;
  const unsigned* succWs  = wsu + OFF_SUCCWS;
  const unsigned* succW2  = wsu + OFF_SUCCW2;
  const unsigned* gateW1  = wsu + OFF_GATEW1;

  __shared__ __align__(16) float    s_prev[4][HD];
  __shared__ __align__(16) unsigned s_prevh[4][96];
  __shared__ __align__(16) unsigned s_sech[4][96];
  __shared__ __align__(16) unsigned s_xh[4][96];
  __shared__ __align__(16) float    s_succ[4][HD];
  __shared__ __align__(16) unsigned s_succh[4][96];
  __shared__ __align__(16) unsigned s_pwh[4][32];
  __shared__ __align__(16) unsigned s_phwh[4][8];
  __shared__ __align__(16) float    s_part[4][256];   // [row][slice*C+col]
  __shared__ __align__(16) float    s_gpart[4][HD];   // [row][col]
  __shared__ int s_tok[4];

  const int tid = threadIdx.x;
  const int b0  = blockIdx.x * 4;
  const int w   = tid >> 6, lane = tid & 63;

  for (int i = tid; i < 4 * HD; i += 256) s_prev[i / HD][i % HD] = 0.f;
  for (int i = tid; i < 4 * 96; i += 256) s_prevh[i / 96][i % 96] = 0u;
  __syncthreads();

  for (int t = 0; t < S_LEN; ++t) {
    if (tid < 4) s_tok[tid] = ids[(b0 + tid) * S_LEN + t];
    __syncthreads();

    // ---- P1: sel pre-activation (prev part), 4 k-slices x 64 cols ----
    {
      int c = tid & 63, sl = tid >> 6;
      float acc[4] = {0.f, 0.f, 0.f, 0.f};
      mm4(selWp + (sl * 24) * PSL + c, PSL, 6, &s_prevh[0][sl * 24], 96, acc);
#pragma unroll
      for (int r = 0; r < 4; ++r) s_part[r][(sl << 6) | c] = acc[r];
    }
    __syncthreads();

    // ---- P2: sel softmax (wave w = row w, 64 lanes = 64 patch slots) ----
    {
      int c = lane;
      float a = sel_tok[s_tok[w] * PSL + c];
#pragma unroll
      for (int s = 0; s < 4; ++s) a += s_part[w][(s << 6) | c];
      float mx = a;
#pragma unroll
      for (int m = 32; m; m >>= 1) mx = fmaxf(mx, __shfl_xor(mx, m));
      float e = expf(a - mx);
      float sm = e;
#pragma unroll
      for (int m = 32; m; m >>= 1) sm += __shfl_xor(sm, m);
      float pv = e / sm;
      out_pw[(size_t)((b0 + w) * S_LEN + t) * PSL + c] = pv;
      float ov = __shfl_xor(pv, 1);
      if (!(c & 1)) s_pwh[w][c >> 1] = pk2(pv, ov);
    }
    __syncthreads();

    // ---- P3: bind1 = tok_table + pw@PB + prev@bindWp; gelu ----
    if (tid < HD) {
      int c = tid;
      float acc[4];
#pragma unroll
      for (int r = 0; r < 4; ++r) acc[r] = bind_tok[s_tok[r] * HD + c];
      mm4(PB + c, HD, 8, &s_pwh[0][0], 32, acc);
      mm4(bindWp + c, HD, 24, &s_prevh[0][0], 96, acc);
#pragma unroll
      for (int r = 0; r < 4; ++r) {
        float g = geluf(acc[r]);
        float o = __shfl_xor(g, 1);
        if (!(c & 1)) s_xh[r][c >> 1] = pk2(g, o);
      }
    }
    __syncthreads();

    // ---- P4: bind2 + tanh -> sec ----
    if (tid < HD) {
      int c = tid;
      float acc[4];
#pragma unroll
      for (int r = 0; r < 4; ++r) acc[r] = bind_b2[c];
      mm4(bindW2 + c, HD, 24, &s_xh[0][0], 96, acc);
#pragma unroll
      for (int r = 0; r < 4; ++r) {
        float sv = tanhf(acc[r]);
        float o = __shfl_xor(sv, 1);
        if (!(c & 1)) s_sech[r][c >> 1] = pk2(sv, o);
      }
    }
    __syncthreads();

    // ---- P5: router pre-activation, 16 k-slices x 16 cols ----
    {
      int c = tid & 15, sl = tid >> 4;
      float acc[4] = {0.f, 0.f, 0.f, 0.f};
      const unsigned* xb = (sl < 8) ? &s_sech[0][sl * 12] : &s_prevh[0][(sl - 8) * 12];
      mm4(routerW + (sl * 12) * PHD + c, PHD, 3, xb, 96, acc);
#pragma unroll
      for (int r = 0; r < 4; ++r) s_part[r][(sl << 4) | c] = acc[r];
    }
    __syncthreads();

    // ---- P6: router softmax (wave w = row w, lanes 0..15) ----
    if (lane < PHD) {
      int c = lane;
      float a = router_b[c];
#pragma unroll
      for (int s = 0; s < 16; ++s) a += s_part[w][(s << 4) | c];
      float mx = a;
#pragma unroll
      for (int m = 8; m; m >>= 1) mx = fmaxf(mx, __shfl_xor(mx, m));
      float e = expf(a - mx);
      float sm = e;
#pragma unroll
      for (int m = 8; m; m >>= 1) sm += __shfl_xor(sm, m);
      float ph = e / sm;
      out_phw[(size_t)((b0 + w) * S_LEN + t) * PHD + c] = ph;
      float ov = __shfl_xor(ph, 1);
      if (!(c & 1)) s_phwh[w][c >> 1] = pk2(ph, ov);
    }
    __syncthreads();

    // ---- P7: succ1 = sec@succWs + pw@PS + phw@PhS + b; gelu ----
    if (tid < HD) {
      int c = tid;
      float acc[4];
#pragma unroll
      for (int r = 0; r < 4; ++r) acc[r] = succ_b1[c];
      mm4(succWs + c, HD, 24, &s_sech[0][0], 96, acc);
      mm4(PS + c, HD, 8, &s_pwh[0][0], 32, acc);
      mm4(PhS + c, HD, 2, &s_phwh[0][0], 8, acc);
#pragma unroll
      for (int r = 0; r < 4; ++r) {
        float g = geluf(acc[r]);
        float o = __shfl_xor(g, 1);
        if (!(c & 1)) s_xh[r][c >> 1] = pk2(g, o);
      }
    }
    __syncthreads();

    // ---- P8: succ2 + tanh -> succ (f32 + f16) ----
    if (tid < HD) {
      int c = tid;
      float acc[4];
#pragma unroll
      for (int r = 0; r < 4; ++r) acc[r] = succ_b2[c];
      mm4(succW2 + c, HD, 24, &s_xh[0][0], 96, acc);
#pragma unroll
      for (int r = 0; r < 4; ++r) {
        float sv = tanhf(acc[r]);
        s_succ[r][c] = sv;
        float o = __shfl_xor(sv, 1);
        if (!(c & 1)) s_succh[r][c >> 1] = pk2(sv, o);
      }
    }
    __syncthreads();

    // ---- P9: gate1 = [succ,prev]@gate_W1 + b; gelu; * gate_W2[c] ----
    if (tid < HD) {
      int c = tid;
      float acc[4];
#pragma unroll
      for (int r = 0; r < 4; ++r) acc[r] = gate_b1[c];
      mm4(gateW1 + c, HD, 24, &s_succh[0][0], 96, acc);
      mm4(gateW1 + 96 * HD + c, HD, 24, &s_prevh[0][0], 96, acc);
      float w2c = gate_W2[c];
#pragma unroll
      for (int r = 0; r < 4; ++r) s_gpart[r][c] = geluf(acc[r]) * w2c;
    }
    __syncthreads();

    // ---- P10+P11: gate reduce, blend, LayerNorm (wave w = row w) ----
    {
      float gp = s_gpart[w][lane] + s_gpart[w][lane + 64] + s_gpart[w][lane + 128];
#pragma unroll
      for (int m = 32; m; m >>= 1) gp += __shfl_xor(gp, m);
      float gv = 1.f / (1.f + expf(-(gp + gate_b2[0])));
      if (lane == 0) out_gate[(size_t)(b0 + w) * S_LEN + t] = gv;

      int c0 = lane, c1 = lane + 64, c2 = lane + 128;
      float h0 = gv * s_succ[w][c0] + (1.f - gv) * s_prev[w][c0];
      float h1 = gv * s_succ[w][c1] + (1.f - gv) * s_prev[w][c1];
      float h2v = gv * s_succ[w][c2] + (1.f - gv) * s_prev[w][c2];
      float sum = h0 + h1 + h2v;
#pragma unroll
      for (int m = 32; m; m >>= 1) sum += __shfl_xor(sum, m);
      float mean = sum * (1.f / 192.f);
      float d0 = h0 - mean, d1 = h1 - mean, d2 = h2v - mean;
      float vs = d0 * d0 + d1 * d1 + d2 * d2;
#pragma unroll
      for (int m = 32; m; m >>= 1) vs += __shfl_xor(vs, m);
      float rstd = rsqrtf(vs * (1.f / 192.f) + 1e-5f);
      float y0 = d0 * rstd * ln_g[c0] + ln_b[c0];
      float y1 = d1 * rstd * ln_g[c1] + ln_b[c1];
      float y2 = d2 * rstd * ln_g[c2] + ln_b[c2];
      size_t ho = (size_t)((b0 + w) * S_LEN + t) * HD;
      out_hidden[ho + c0] = y0;
      out_hidden[ho + c1] = y1;
      out_hidden[ho + c2] = y2;
      s_prev[w][c0] = y0; s_prev[w][c1] = y1; s_prev[w][c2] = y2;
      float o0 = __shfl_xor(y0, 1), o1 = __shfl_xor(y1, 1), o2 = __shfl_xor(y2, 1);
      if (!(lane & 1)) {
        s_prevh[w][c0 >> 1] = pk2(y0, o0);
        s_prevh[w][c1 >> 1] = pk2(y1, o1);
        s_prevh[w][c2 >> 1] = pk2(y2, o2);
      }
    }
    __syncthreads();
  }
}

// ---------------------------------------------------------------------------
// dec kernel: logits[65536,256] = hidden[65536,192] @ dec_W[192,256]
// 1024 blocks x 256 threads; 64 rows per block; dec_W column in registers
// ---------------------------------------------------------------------------
__global__ __launch_bounds__(256) void dec_k(
    const float* __restrict__ hid, const unsigned* __restrict__ dec2,
    float* __restrict__ logits)
{
  __shared__ __align__(16) unsigned sA[64][96];
  int tid = threadIdx.x;
  size_t r0 = (size_t)blockIdx.x * 64;

#pragma unroll
  for (int i = 0; i < 24; ++i) {
    int idx = i * 256 + tid;
    int rr = idx / 96, kk = idx % 96;
    const float2* hp = (const float2*)(hid + (r0 + rr) * HD);
    float2 v = hp[kk];
    sA[rr][kk] = pk2(v.x, v.y);
  }
  __syncthreads();

  int c = tid;
  unsigned wr[96];
#pragma unroll
  for (int k = 0; k < 96; ++k) wr[k] = dec2[k * VOC + c];

  for (int rr = 0; rr < 64; ++rr) {
    float acc = 0.f;
#pragma unroll
    for (int k4 = 0; k4 < 24; ++k4) {
      uint4 xv = *reinterpret_cast<const uint4*>(&sA[rr][k4 * 4]);
      acc = dot2f(wr[4 * k4 + 0], xv.x, acc);
      acc = dot2f(wr[4 * k4 + 1], xv.y, acc);
      acc = dot2f(wr[4 * k4 + 2], xv.z, acc);
      acc = dot2f(wr[4 * k4 + 3], xv.w, acc);
    }
    logits[(r0 + rr) * VOC + c] = acc;
  }
}

// ---------------------------------------------------------------------------
extern "C" void kernel_launch(void* const* d_in, const int* in_sizes, int n_in,
                              void* d_out, int out_size, void* d_ws, size_t ws_size,
                              hipStream_t stream)
{
  const int*   ids  = (const int*)d_in[0];
  const float* emb  = (const float*)d_in[1];
  const float* selW = (const float*)d_in[2];
  const float* selb = (const float*)d_in[3];
  const float* PV   = (const float*)d_in[4];
  const float* bW1  = (const float*)d_in[5];
  const float* bb1  = (const float*)d_in[6];
  const float* bW2  = (const float*)d_in[7];
  const float* bb2  = (const float*)d_in[8];
  const float* phE  = (const float*)d_in[9];
  const float* rW   = (const float*)d_in[10];
  const float* rb   = (const float*)d_in[11];
  const float* sW1  = (const float*)d_in[12];
  const float* sb1  = (const float*)d_in[13];
  const float* sW2  = (const float*)d_in[14];
  const float* sb2  = (const float*)d_in[15];
  const float* gW1  = (const float*)d_in[16];
  const float* gb1  = (const float*)d_in[17];
  const float* gW2  = (const float*)d_in[18];
  const float* gb2  = (const float*)d_in[19];
  const float* lng  = (const float*)d_in[20];
  const float* lnb  = (const float*)d_in[21];
  const float* decW = (const float*)d_in[22];

  float* out = (float*)d_out;
  float* o_logits = out;                         // [512][128][256]
  float* o_hidden = out + 16777216;              // [512][128][192]
  float* o_pw     = out + 29360128;              // [512][128][64]
  float* o_phw    = out + 33554432;              // [512][128][16]
  float* o_gate   = out + 34603008;              // [512][128][1]

  float* ws = (float*)d_ws;

  hipLaunchKernelGGL(fold_k, dim3(874), dim3(256), 0, stream,
                     emb, selW, selb, PV, bW1, bb1, bW2, phE, rW, sW1, sW2, gW1, decW, ws);
  hipLaunchKernelGGL(rnn_k, dim3(128), dim3(256), 0, stream,
                     ids, ws, bb2, rb, sb1, sb2, gb1, gW2, gb2, lng, lnb,
                     o_hidden, o_pw, o_phw, o_gate);
  hipLaunchKernelGGL(dec_k, dim3(1024), dim3(256), 0, stream,
                     o_hidden, ((const unsigned*)d_ws) + OFF_DEC, o_logits);
}

// Round 3
// 2183.565 us; speedup vs baseline: 14.4139x; 1.8895x over previous
//
#include <hip/hip_runtime.h>
#include <stdint.h>
#include <math.h>

// ---------------------------------------------------------------------------
// SpikeICSPBLMMinimal: 128-step scan RNN. B=512, S=128, H=192, V=256, P=64, PH=16
// Kernel 1 (fold_k): algebraic folding + f16 k-pair packing of all weights
// Kernel 2 (rnn_k):  persistent per-batch-row scan; 128 blocks x 4 rows
// Kernel 3 (dec_k):  logits = hidden @ dec_W as parallel GEMM (deferred)
//
// R1: unroll-2 on mm4 (kill spills); conflict-free partial layout.
// R2: 1024-thread blocks (16 waves -> 4 waves/SIMD, was 1/SIMD at VALUBusy
// 7.8%), split-K x4 per matmul phase (12 waves: 4 k-slices x 3 col-groups)
// + reduce/activate/pack sub-phase. Serial dot2 per step ~2700 -> ~700.
// ---------------------------------------------------------------------------

#define S_LEN 128
#define HD    192
#define VOC   256
#define PSL   64
#define PHD   16

// ws layout (in 4-byte elements)
#define OFF_SELTOK   0         // f32 [256][64]   tok@sel_W_tok + sel_b
#define OFF_BINDTOK  16384     // f32 [256][192]  tok@bind_W1_tok + bind_b1
#define OFF_SELWP    65536     // u32 [96][64]    sel_W prev-part, f16 k-pairs
#define OFF_PB       71680     // u32 [32][192]   PV@bind_W1_patch
#define OFF_BINDWP   77824     // u32 [96][192]   bind_W1 prev-part
#define OFF_BINDW2   96256     // u32 [96][192]
#define OFF_ROUTERW  114688    // u32 [192][16]   router_W (sec rows then prev rows)
#define OFF_PS       117760    // u32 [32][192]   PV@succ_W1_patch
#define OFF_PHS      123904    // u32 [8][192]    phase_embed@succ_W1_phs
#define OFF_SUCCWS   125440    // u32 [96][192]   succ_W1 sec-part
#define OFF_SUCCW2   143872    // u32 [96][192]
#define OFF_GATEW1   162304    // u32 [192][192]  gate_W1 (succ rows then prev rows)
#define OFF_DEC      199168    // u32 [96][256]   dec_W
#define WS_TOTAL     223744

typedef _Float16 h2 __attribute__((ext_vector_type(2)));

__device__ __forceinline__ float dot2f(unsigned w, unsigned x, float c) {
  h2 hw = __builtin_bit_cast(h2, w);
  h2 hx = __builtin_bit_cast(h2, x);
#if __has_builtin(__builtin_amdgcn_fdot2)
  return __builtin_amdgcn_fdot2(hw, hx, c, false);
#else
  return c + (float)hw.x * (float)hx.x + (float)hw.y * (float)hx.y;
#endif
}

__device__ __forceinline__ unsigned pk2(float a, float b) {
  _Float16 ha = (_Float16)a, hb = (_Float16)b;           // RTN converts
  unsigned short ua = __builtin_bit_cast(unsigned short, ha);
  unsigned short ub = __builtin_bit_cast(unsigned short, hb);
  return (unsigned)ua | ((unsigned)ub << 16);
}

__device__ __forceinline__ float geluf(float x) {
  return 0.5f * x * (1.0f + erff(x * 0.70710678118654752f));  // exact erf gelu
}

// ---------------------------------------------------------------------------
// fold kernel: region-dispatch by blockIdx.x (874 blocks x 256 threads)
// ---------------------------------------------------------------------------
__global__ __launch_bounds__(256) void fold_k(
    const float* __restrict__ emb,  const float* __restrict__ selW,
    const float* __restrict__ selb, const float* __restrict__ PV,
    const float* __restrict__ bW1,  const float* __restrict__ bb1,
    const float* __restrict__ bW2,  const float* __restrict__ phE,
    const float* __restrict__ rW,   const float* __restrict__ sW1,
    const float* __restrict__ sW2,  const float* __restrict__ gW1,
    const float* __restrict__ decW, float* __restrict__ ws)
{
  unsigned* wsu = (unsigned*)ws;
  int blk = blockIdx.x, tid = threadIdx.x;

  if (blk < 64) {                       // sel_tok [256][64] f32
    int o = blk * 256 + tid; int v = o >> 6, c = o & 63;
    float a = selb[c];
    const float* er = emb + v * HD;
    for (int h = 0; h < HD; ++h) a += er[h] * selW[h * PSL + c];
    ws[OFF_SELTOK + o] = a;
  } else if (blk < 256) {               // bind_tok [256][192] f32
    int o = (blk - 64) * 256 + tid; int v = o / HD, c = o % HD;
    float a = bb1[c];
    const float* er = emb + v * HD;
    for (int h = 0; h < HD; ++h) a += er[h] * bW1[h * HD + c];
    ws[OFF_BINDTOK + o] = a;
  } else if (blk < 280) {               // PB2: PV @ bind_W1[192:384]
    int o = (blk - 256) * 256 + tid; int k2 = o / HD, c = o % HD;
    float lo = 0.f, hi = 0.f;
    const float* p0 = PV + (2 * k2) * HD; const float* p1 = p0 + HD;
    for (int h = 0; h < HD; ++h) { float wv = bW1[(HD + h) * HD + c]; lo += p0[h] * wv; hi += p1[h] * wv; }
    wsu[OFF_PB + o] = pk2(lo, hi);
  } else if (blk < 304) {               // PS2: PV @ succ_W1[192:384]
    int o = (blk - 280) * 256 + tid; int k2 = o / HD, c = o % HD;
    float lo = 0.f, hi = 0.f;
    const float* p0 = PV + (2 * k2) * HD; const float* p1 = p0 + HD;
    for (int h = 0; h < HD; ++h) { float wv = sW1[(HD + h) * HD + c]; lo += p0[h] * wv; hi += p1[h] * wv; }
    wsu[OFF_PS + o] = pk2(lo, hi);
  } else if (blk < 310) {               // PhS2: phase_embed @ succ_W1[384:576]
    int o = (blk - 304) * 256 + tid; int k2 = o / HD, c = o % HD;
    float lo = 0.f, hi = 0.f;
    const float* p0 = phE + (2 * k2) * HD; const float* p1 = p0 + HD;
    for (int h = 0; h < HD; ++h) { float wv = sW1[(2 * HD + h) * HD + c]; lo += p0[h] * wv; hi += p1[h] * wv; }
    wsu[OFF_PHS + o] = pk2(lo, hi);
  } else if (blk < 334) {               // selWp2 [96][64] from sel_W rows 192..383
    int o = (blk - 310) * 256 + tid; int k2 = o >> 6, c = o & 63;
    wsu[OFF_SELWP + o] = pk2(selW[(HD + 2 * k2) * PSL + c], selW[(HD + 2 * k2 + 1) * PSL + c]);
  } else if (blk < 406) {               // bindWp2 [96][192] from bind_W1 rows 384..575
    int o = (blk - 334) * 256 + tid; int k2 = o / HD, c = o % HD;
    wsu[OFF_BINDWP + o] = pk2(bW1[(2 * HD + 2 * k2) * HD + c], bW1[(2 * HD + 2 * k2 + 1) * HD + c]);
  } else if (blk < 478) {               // bindW2p [96][192]
    int o = (blk - 406) * 256 + tid; int k2 = o / HD, c = o % HD;
    wsu[OFF_BINDW2 + o] = pk2(bW2[(2 * k2) * HD + c], bW2[(2 * k2 + 1) * HD + c]);
  } else if (blk < 490) {               // routerW2 [192][16] (rows 0..383 paired)
    int o = (blk - 478) * 256 + tid; int k2 = o >> 4, c = o & 15;
    wsu[OFF_ROUTERW + o] = pk2(rW[(2 * k2) * PHD + c], rW[(2 * k2 + 1) * PHD + c]);
  } else if (blk < 562) {               // succWs2 [96][192] from succ_W1 rows 0..191
    int o = (blk - 490) * 256 + tid; int k2 = o / HD, c = o % HD;
    wsu[OFF_SUCCWS + o] = pk2(sW1[(2 * k2) * HD + c], sW1[(2 * k2 + 1) * HD + c]);
  } else if (blk < 634) {               // succW2p [96][192]
    int o = (blk - 562) * 256 + tid; int k2 = o / HD, c = o % HD;
    wsu[OFF_SUCCW2 + o] = pk2(sW2[(2 * k2) * HD + c], sW2[(2 * k2 + 1) * HD + c]);
  } else if (blk < 778) {               // gateW12 [192][192] (rows 0..383 paired)
    int o = (blk - 634) * 256 + tid; int k2 = o / HD, c = o % HD;
    wsu[OFF_GATEW1 + o] = pk2(gW1[(2 * k2) * HD + c], gW1[(2 * k2 + 1) * HD + c]);
  } else {                              // dec2 [96][256]
    int o = (blk - 778) * 256 + tid; int k2 = o >> 8, c = o & 255;
    wsu[OFF_DEC + o] = pk2(decW[(2 * k2) * VOC + c], decW[(2 * k2 + 1) * VOC + c]);
  }
}

// ---------------------------------------------------------------------------
// mm4: 4-row dot2 accumulation. wp pre-offset by column; x is LDS f16-pair
// buffer (row stride xs u32). nk4 chunks of 4 k-pairs.
// unroll 2: full unroll spilled (R1: ~250 dw/thread scratch)
// ---------------------------------------------------------------------------
__device__ __forceinline__ void mm4(const unsigned* __restrict__ wp, int ldw, int nk4,
                                    const unsigned* __restrict__ x, int xs, float acc[4])
{
#pragma unroll 2
  for (int kk = 0; kk < nk4; ++kk) {
    unsigned w0 = wp[0], w1 = wp[ldw], w2 = wp[2 * ldw], w3 = wp[3 * ldw];
    wp += 4 * ldw;
    const unsigned* xp = x + kk * 4;
#pragma unroll
    for (int r = 0; r < 4; ++r) {
      uint4 xv = *reinterpret_cast<const uint4*>(xp + r * xs);
      acc[r] = dot2f(w0, xv.x, acc[r]);
      acc[r] = dot2f(w1, xv.y, acc[r]);
      acc[r] = dot2f(w2, xv.z, acc[r]);
      acc[r] = dot2f(w3, xv.w, acc[r]);
    }
  }
}

// ---------------------------------------------------------------------------
// rnn kernel: 128 blocks x 1024 threads (16 waves), 4 batch rows per block.
// Matmul phases: 12 waves = 4 k-slices x 3 col-groups(64); partials in LDS;
// reduce+activation+f16-pack sub-phase per matmul.
// ---------------------------------------------------------------------------
__global__ __launch_bounds__(1024) void rnn_k(
    const int* __restrict__ ids, const float* __restrict__ ws,
    const float* __restrict__ bind_b2, const float* __restrict__ router_b,
    const float* __restrict__ succ_b1, const float* __restrict__ succ_b2,
    const float* __restrict__ gate_b1, const float* __restrict__ gate_W2,
    const float* __restrict__ gate_b2, const float* __restrict__ ln_g,
    const float* __restrict__ ln_b,
    float* __restrict__ out_hidden, float* __restrict__ out_pw,
    float* __restrict__ out_phw, float* __restrict__ out_gate)
{
  const unsigned* wsu = (const unsigned*)ws;
  const float* sel_tok  = ws + OFF_SELTOK;
  const float* bind_tok = ws + OFF_BINDTOK;
  const unsigned* selWp   = wsu + OFF_SELWP;
  const unsigned* PB      = wsu + OFF_PB;
  const unsigned* bindWp  = wsu + OFF_BINDWP;
  const unsigned* bindW2  = wsu + OFF_BINDW2;
  const unsigned* routerW = wsu + OFF_ROUTERW;
  const unsigned* PS      = wsu + OFF_PS;
  const unsigned* PhS     = wsu + OFF_PHS;
  const unsigned* succWs  = wsu + OFF_SUCCWS;
  const unsigned* succW2  = wsu + OFF_SUCCW2;
  const unsigned* gateW1  = wsu + OFF_GATEW1;

  __shared__ __align__(16) float    s_prev[4][HD];
  __shared__ __align__(16) unsigned s_prevh[4][96];
  __shared__ __align__(16) unsigned s_sech[4][96];
  __shared__ __align__(16) unsigned s_xh[4][96];
  __shared__ __align__(16) float    s_succ[4][HD];
  __shared__ __align__(16) unsigned s_succh[4][96];
  __shared__ __align__(16) unsigned s_pwh[4][32];
  __shared__ __align__(16) unsigned s_phwh[4][8];
  __shared__ __align__(16) float    s_part[3072];     // split-K partials
  __shared__ __align__(16) float    s_gpart[4][HD];
  __shared__ int s_tok[4];

  const int tid  = threadIdx.x;
  const int b0   = blockIdx.x * 4;
  const int u    = tid >> 6, lane = tid & 63;
  // matmul-phase mapping: 12 active waves = slice s (0..3) x col-group (0..2)
  const int ms   = u & 3;
  const int mc   = ((u >> 2) << 6) + lane;   // column 0..191 (u<12)
  // reduce-phase mapping: 12 active waves = row r (0..3) x col-group (0..2)
  const int rr   = u & 3;
  const int rc   = mc;

  for (int i = tid; i < 4 * HD; i += 1024) s_prev[i / HD][i % HD] = 0.f;
  for (int i = tid; i < 4 * 96; i += 1024) s_prevh[i / 96][i % 96] = 0u;
  __syncthreads();

  for (int t = 0; t < S_LEN; ++t) {
    if (tid < 4) s_tok[tid] = ids[(b0 + tid) * S_LEN + t];
    __syncthreads();

    // ---- P1: sel prev-part partials: 8 slices x 12 kpairs x 64 cols ----
    if (u < 8) {
      int c = lane, s = u;
      float acc[4] = {0.f, 0.f, 0.f, 0.f};
      mm4(selWp + (s * 12) * PSL + c, PSL, 3, &s_prevh[0][s * 12], 96, acc);
#pragma unroll
      for (int r = 0; r < 4; ++r) s_part[((r << 3) | s) * 64 + c] = acc[r];
    }
    __syncthreads();

    // ---- P2: sel softmax (wave u = row, 64 lanes = patch slots) ----
    if (u < 4) {
      int c = lane;
      float a = sel_tok[s_tok[u] * PSL + c];
#pragma unroll
      for (int s = 0; s < 8; ++s) a += s_part[((u << 3) | s) * 64 + c];
      float mx = a;
#pragma unroll
      for (int m = 32; m; m >>= 1) mx = fmaxf(mx, __shfl_xor(mx, m));
      float e = expf(a - mx);
      float sm = e;
#pragma unroll
      for (int m = 32; m; m >>= 1) sm += __shfl_xor(sm, m);
      float pv = e / sm;
      out_pw[(size_t)((b0 + u) * S_LEN + t) * PSL + c] = pv;
      float ov = __shfl_xor(pv, 1);
      if (!(c & 1)) s_pwh[u][c >> 1] = pk2(pv, ov);
    }
    __syncthreads();

    // ---- P3: bind1 partials ----
    if (u < 12) {
      float acc[4] = {0.f, 0.f, 0.f, 0.f};
      mm4(PB + (ms * 8) * HD + mc, HD, 2, &s_pwh[0][ms * 8], 32, acc);
      mm4(bindWp + (ms * 24) * HD + mc, HD, 6, &s_prevh[0][ms * 24], 96, acc);
#pragma unroll
      for (int r = 0; r < 4; ++r) s_part[((r << 2) | ms) * 192 + mc] = acc[r];
    }
    __syncthreads();
    // ---- P3b: reduce + tok table + gelu + pack ----
    if (u < 12) {
      float v = bind_tok[s_tok[rr] * HD + rc];
#pragma unroll
      for (int s = 0; s < 4; ++s) v += s_part[((rr << 2) | s) * 192 + rc];
      float g = geluf(v);
      float o = __shfl_xor(g, 1);
      if (!(lane & 1)) s_xh[rr][rc >> 1] = pk2(g, o);
    }
    __syncthreads();

    // ---- P4: bind2 partials ----
    if (u < 12) {
      float acc[4] = {0.f, 0.f, 0.f, 0.f};
      mm4(bindW2 + (ms * 24) * HD + mc, HD, 6, &s_xh[0][ms * 24], 96, acc);
#pragma unroll
      for (int r = 0; r < 4; ++r) s_part[((r << 2) | ms) * 192 + mc] = acc[r];
    }
    __syncthreads();
    // ---- P4b: reduce + bias + tanh -> sec ----
    if (u < 12) {
      float v = bind_b2[rc];
#pragma unroll
      for (int s = 0; s < 4; ++s) v += s_part[((rr << 2) | s) * 192 + rc];
      float sv = tanhf(v);
      float o = __shfl_xor(sv, 1);
      if (!(lane & 1)) s_sech[rr][rc >> 1] = pk2(sv, o);
    }
    __syncthreads();

    // ---- P5: router partials: 16 slices x 12 kpairs x 16 cols ----
    if (tid < 256) {
      int c = tid & 15, sl = tid >> 4;
      float acc[4] = {0.f, 0.f, 0.f, 0.f};
      const unsigned* xb = (sl < 8) ? &s_sech[0][sl * 12] : &s_prevh[0][(sl - 8) * 12];
      mm4(routerW + (sl * 12) * PHD + c, PHD, 3, xb, 96, acc);
#pragma unroll
      for (int r = 0; r < 4; ++r) s_part[r * 256 + sl * 16 + c] = acc[r];
    }
    __syncthreads();

    // ---- P6: router softmax (wave u = row, lanes 0..15) ----
    if (u < 4 && lane < PHD) {
      int c = lane;
      float a = router_b[c];
#pragma unroll
      for (int s = 0; s < 16; ++s) a += s_part[u * 256 + s * 16 + c];
      float mx = a;
#pragma unroll
      for (int m = 8; m; m >>= 1) mx = fmaxf(mx, __shfl_xor(mx, m));
      float e = expf(a - mx);
      float sm = e;
#pragma unroll
      for (int m = 8; m; m >>= 1) sm += __shfl_xor(sm, m);
      float ph = e / sm;
      out_phw[(size_t)((b0 + u) * S_LEN + t) * PHD + c] = ph;
      float ov = __shfl_xor(ph, 1);
      if (!(c & 1)) s_phwh[u][c >> 1] = pk2(ph, ov);
    }
    __syncthreads();

    // ---- P7: succ1 partials (sec part + patch part) ----
    if (u < 12) {
      float acc[4] = {0.f, 0.f, 0.f, 0.f};
      mm4(succWs + (ms * 24) * HD + mc, HD, 6, &s_sech[0][ms * 24], 96, acc);
      mm4(PS + (ms * 8) * HD + mc, HD, 2, &s_pwh[0][ms * 8], 32, acc);
#pragma unroll
      for (int r = 0; r < 4; ++r) s_part[((r << 2) | ms) * 192 + mc] = acc[r];
    }
    __syncthreads();
    // ---- P7b: reduce + bias + phase part + gelu + pack ----
    if (u < 12) {
      float v = succ_b1[rc];
#pragma unroll
      for (int s = 0; s < 4; ++s) v += s_part[((rr << 2) | s) * 192 + rc];
#pragma unroll
      for (int k = 0; k < 8; ++k) v = dot2f(PhS[k * HD + rc], s_phwh[rr][k], v);
      float g = geluf(v);
      float o = __shfl_xor(g, 1);
      if (!(lane & 1)) s_xh[rr][rc >> 1] = pk2(g, o);
    }
    __syncthreads();

    // ---- P8: succ2 partials ----
    if (u < 12) {
      float acc[4] = {0.f, 0.f, 0.f, 0.f};
      mm4(succW2 + (ms * 24) * HD + mc, HD, 6, &s_xh[0][ms * 24], 96, acc);
#pragma unroll
      for (int r = 0; r < 4; ++r) s_part[((r << 2) | ms) * 192 + mc] = acc[r];
    }
    __syncthreads();
    // ---- P8b: reduce + bias + tanh -> succ (f32 + packed) ----
    if (u < 12) {
      float v = succ_b2[rc];
#pragma unroll
      for (int s = 0; s < 4; ++s) v += s_part[((rr << 2) | s) * 192 + rc];
      float sv = tanhf(v);
      s_succ[rr][rc] = sv;
      float o = __shfl_xor(sv, 1);
      if (!(lane & 1)) s_succh[rr][rc >> 1] = pk2(sv, o);
    }
    __syncthreads();

    // ---- P9: gate1 partials (succ part + prev part) ----
    if (u < 12) {
      float acc[4] = {0.f, 0.f, 0.f, 0.f};
      mm4(gateW1 + (ms * 24) * HD + mc, HD, 6, &s_succh[0][ms * 24], 96, acc);
      mm4(gateW1 + (96 + ms * 24) * HD + mc, HD, 6, &s_prevh[0][ms * 24], 96, acc);
#pragma unroll
      for (int r = 0; r < 4; ++r) s_part[((r << 2) | ms) * 192 + mc] = acc[r];
    }
    __syncthreads();
    // ---- P9b: reduce + bias + gelu * gate_W2 ----
    if (u < 12) {
      float v = gate_b1[rc];
#pragma unroll
      for (int s = 0; s < 4; ++s) v += s_part[((rr << 2) | s) * 192 + rc];
      s_gpart[rr][rc] = geluf(v) * gate_W2[rc];
    }
    __syncthreads();

    // ---- P10: gate reduce, blend, LayerNorm (wave u = row) ----
    if (u < 4) {
      int w = u;
      float gp = s_gpart[w][lane] + s_gpart[w][lane + 64] + s_gpart[w][lane + 128];
#pragma unroll
      for (int m = 32; m; m >>= 1) gp += __shfl_xor(gp, m);
      float gv = 1.f / (1.f + expf(-(gp + gate_b2[0])));
      if (lane == 0) out_gate[(size_t)(b0 + w) * S_LEN + t] = gv;

      int c0 = lane, c1 = lane + 64, c2 = lane + 128;
      float h0 = gv * s_succ[w][c0] + (1.f - gv) * s_prev[w][c0];
      float h1 = gv * s_succ[w][c1] + (1.f - gv) * s_prev[w][c1];
      float h2v = gv * s_succ[w][c2] + (1.f - gv) * s_prev[w][c2];
      float sum = h0 + h1 + h2v;
#pragma unroll
      for (int m = 32; m; m >>= 1) sum += __shfl_xor(sum, m);
      float mean = sum * (1.f / 192.f);
      float d0 = h0 - mean, d1 = h1 - mean, d2 = h2v - mean;
      float vs = d0 * d0 + d1 * d1 + d2 * d2;
#pragma unroll
      for (int m = 32; m; m >>= 1) vs += __shfl_xor(vs, m);
      float rstd = rsqrtf(vs * (1.f / 192.f) + 1e-5f);
      float y0 = d0 * rstd * ln_g[c0] + ln_b[c0];
      float y1 = d1 * rstd * ln_g[c1] + ln_b[c1];
      float y2 = d2 * rstd * ln_g[c2] + ln_b[c2];
      size_t ho = (size_t)((b0 + w) * S_LEN + t) * HD;
      out_hidden[ho + c0] = y0;
      out_hidden[ho + c1] = y1;
      out_hidden[ho + c2] = y2;
      s_prev[w][c0] = y0; s_prev[w][c1] = y1; s_prev[w][c2] = y2;
      float o0 = __shfl_xor(y0, 1), o1 = __shfl_xor(y1, 1), o2 = __shfl_xor(y2, 1);
      if (!(lane & 1)) {
        s_prevh[w][c0 >> 1] = pk2(y0, o0);
        s_prevh[w][c1 >> 1] = pk2(y1, o1);
        s_prevh[w][c2 >> 1] = pk2(y2, o2);
      }
    }
    __syncthreads();
  }
}

// ---------------------------------------------------------------------------
// dec kernel: logits[65536,256] = hidden[65536,192] @ dec_W[192,256]
// 1024 blocks x 256 threads; 64 rows per block; dec_W column in registers
// ---------------------------------------------------------------------------
__global__ __launch_bounds__(256) void dec_k(
    const float* __restrict__ hid, const unsigned* __restrict__ dec2,
    float* __restrict__ logits)
{
  __shared__ __align__(16) unsigned sA[64][96];
  int tid = threadIdx.x;
  size_t r0 = (size_t)blockIdx.x * 64;

#pragma unroll
  for (int i = 0; i < 24; ++i) {
    int idx = i * 256 + tid;
    int rr = idx / 96, kk = idx % 96;
    const float2* hp = (const float2*)(hid + (r0 + rr) * HD);
    float2 v = hp[kk];
    sA[rr][kk] = pk2(v.x, v.y);
  }
  __syncthreads();

  int c = tid;
  unsigned wr[96];
#pragma unroll
  for (int k = 0; k < 96; ++k) wr[k] = dec2[k * VOC + c];

  for (int rr = 0; rr < 64; ++rr) {
    float acc = 0.f;
#pragma unroll
    for (int k4 = 0; k4 < 24; ++k4) {
      uint4 xv = *reinterpret_cast<const uint4*>(&sA[rr][k4 * 4]);
      acc = dot2f(wr[4 * k4 + 0], xv.x, acc);
      acc = dot2f(wr[4 * k4 + 1], xv.y, acc);
      acc = dot2f(wr[4 * k4 + 2], xv.z, acc);
      acc = dot2f(wr[4 * k4 + 3], xv.w, acc);
    }
    logits[(r0 + rr) * VOC + c] = acc;
  }
}

// ---------------------------------------------------------------------------
extern "C" void kernel_launch(void* const* d_in, const int* in_sizes, int n_in,
                              void* d_out, int out_size, void* d_ws, size_t ws_size,
                              hipStream_t stream)
{
  const int*   ids  = (const int*)d_in[0];
  const float* emb  = (const float*)d_in[1];
  const float* selW = (const float*)d_in[2];
  const float* selb = (const float*)d_in[3];
  const float* PV   = (const float*)d_in[4];
  const float* bW1  = (const float*)d_in[5];
  const float* bb1  = (const float*)d_in[6];
  const float* bW2  = (const float*)d_in[7];
  const float* bb2  = (const float*)d_in[8];
  const float* phE  = (const float*)d_in[9];
  const float* rW   = (const float*)d_in[10];
  const float* rb   = (const float*)d_in[11];
  const float* sW1  = (const float*)d_in[12];
  const float* sb1  = (const float*)d_in[13];
  const float* sW2  = (const float*)d_in[14];
  const float* sb2  = (const float*)d_in[15];
  const float* gW1  = (const float*)d_in[16];
  const float* gb1  = (const float*)d_in[17];
  const float* gW2  = (const float*)d_in[18];
  const float* gb2  = (const float*)d_in[19];
  const float* lng  = (const float*)d_in[20];
  const float* lnb  = (const float*)d_in[21];
  const float* decW = (const float*)d_in[22];

  float* out = (float*)d_out;
  float* o_logits = out;                         // [512][128][256]
  float* o_hidden = out + 16777216;              // [512][128][192]
  float* o_pw     = out + 29360128;              // [512][128][64]
  float* o_phw    = out + 33554432;              // [512][128][16]
  float* o_gate   = out + 34603008;              // [512][128][1]

  float* ws = (float*)d_ws;

  hipLaunchKernelGGL(fold_k, dim3(874), dim3(256), 0, stream,
                     emb, selW, selb, PV, bW1, bb1, bW2, phE, rW, sW1, sW2, gW1, decW, ws);
  hipLaunchKernelGGL(rnn_k, dim3(128), dim3(1024), 0, stream,
                     ids, ws, bb2, rb, sb1, sb2, gb1, gW2, gb2, lng, lnb,
                     o_hidden, o_pw, o_phw, o_gate);
  hipLaunchKernelGGL(dec_k, dim3(1024), dim3(256), 0, stream,
                     o_hidden, ((const unsigned*)d_ws) + OFF_DEC, o_logits);
}